// Round 13
// baseline (315.663 us; speedup 1.0000x reference)
//
#include <hip/hip_runtime.h>

typedef unsigned short ushort_t;
typedef unsigned int uint_t;

typedef __bf16 bf16x8 __attribute__((ext_vector_type(8)));
typedef float f32x4 __attribute__((ext_vector_type(4)));

union BFU { ushort_t u; __bf16 h; };

__device__ __forceinline__ float bf2f(uint_t u) {
    union { uint_t i; float f; } v; v.i = u << 16; return v.f;
}
__device__ __forceinline__ ushort_t f2bf(float f) {
    union { float f; uint_t i; } v; v.f = f;
    uint_t r = v.i + 0x7fffu + ((v.i >> 16) & 1u);
    return (ushort_t)(r >> 16);
}
// mode: 1 = bf16 storage, 0 = fp32 storage
__device__ __forceinline__ float loadF(const void* p, size_t i, int isBf16) {
    return isBf16 ? bf2f((uint_t)((const ushort_t*)p)[i]) : ((const float*)p)[i];
}

// flags[0..10]: x,W1,b1,W2,b2,W3,b3,Wres,bres,Wlin,blin  (1=bf16, 0=fp32)
// flags[11]: edge_index is int64 (1) or int32 (0)
struct DetectArgs {
    const void* t[11];
    int elems[11];
    const int* ei;
    int* flags;
};

__device__ __forceinline__ int detect_one(const void* p, int elems) {
    const uint_t* w = (const uint_t*)p;
    int n = elems / 2; if (n > 64) n = 64;
    int cnt = 0;
    for (int k = 0; k < n; ++k) {
        uint_t f = (w[k] >> 7) & 0xFFu;
        cnt += (f >= 100u && f <= 135u);
    }
    return (cnt * 10 >= n * 6) ? 1 : 0;
}

// ---------------- weight pack + dtype detection ----------------
__global__ void k_pack(DetectArgs a,
                       ushort_t* __restrict__ Tcat, ushort_t* __restrict__ T2,
                       ushort_t* __restrict__ T3, ushort_t* __restrict__ Tl) {
    __shared__ int lflag;
    int i = blockIdx.x * blockDim.x + threadIdx.x;
    const int SQ = 128 * 128;
    int m = (i < 4 * SQ) ? (i / SQ) : 4;          // uniform per block (SQ%256==0)
    int fid = (m == 0) ? 1 : (m == 1) ? 3 : (m == 2) ? 5 : (m == 3) ? 7 : 9;
    const void* W = a.t[fid];

    if (threadIdx.x == 0) lflag = detect_one(W, a.elems[fid]);
    if (blockIdx.x == 0 && threadIdx.x >= 64 && threadIdx.x < 75) {
        int t = threadIdx.x - 64;
        a.flags[t] = detect_one(a.t[t], a.elems[t]);
    }
    if (blockIdx.x == 0 && threadIdx.x == 75) {
        int nz = 0;
        for (int k = 0; k < 64; ++k) nz += (a.ei[2 * k + 1] != 0);
        a.flags[11] = (nz == 0) ? 1 : 0;
    }
    __syncthreads();
    int isb = lflag;

    if (i < 4 * SQ) {
        int r = i % SQ;
        int k = r / 128, f = r % 128;
        ushort_t* T = (m == 0) ? Tcat : (m == 1) ? T2 : (m == 2) ? T3 : (Tcat + SQ);
        T[f * 128 + k] = f2bf(loadF(W, (size_t)k * 128 + f, isb));
    } else if (i < 4 * SQ + 128 * 64) {
        int r = i - 4 * SQ;
        int k = r / 64, f = r % 64;
        Tl[f * 128 + k] = f2bf(loadF(W, (size_t)k * 64 + f, isb));
    }
}

// ---------------- degree + rank: the ONLY atomic pass ----------------
__global__ void k_deg(const int* __restrict__ ei, int E, int N,
                      const int* __restrict__ flags, int* __restrict__ deg,
                      int2* __restrict__ tmp) {
    int i = blockIdx.x * blockDim.x + threadIdx.x;
    int e0 = i * 4;
    if (e0 >= E) return;
    int is64 = flags[11];
    if (e0 + 3 < E && (E & 3) == 0) {
        int d[4];
        if (is64) {
            int4 va = *(const int4*)(ei + 2 * E + 2 * e0);
            int4 vb = *(const int4*)(ei + 2 * E + 2 * e0 + 4);
            d[0] = va.x; d[1] = va.z; d[2] = vb.x; d[3] = vb.z;
        } else {
            int4 va = *(const int4*)(ei + E + e0);
            d[0] = va.x; d[1] = va.y; d[2] = va.z; d[3] = va.w;
        }
        int l[4]; bool ok[4];
#pragma unroll
        for (int k = 0; k < 4; ++k) ok[k] = (unsigned)d[k] < (unsigned)N;
#pragma unroll
        for (int k = 0; k < 4; ++k)
            l[k] = ok[k] ? atomicAdd(&deg[d[k]], 1) : 0;
        int4 t01, t23;
        t01.x = ok[0] ? d[0] : -1; t01.y = l[0];
        t01.z = ok[1] ? d[1] : -1; t01.w = l[1];
        t23.x = ok[2] ? d[2] : -1; t23.y = l[2];
        t23.z = ok[3] ? d[3] : -1; t23.w = l[3];
        *(int4*)(tmp + e0) = t01;
        *(int4*)(tmp + e0 + 2) = t23;
    } else {
        for (int e = e0; e < E && e < e0 + 4; ++e) {
            int dd = is64 ? ei[2 * E + 2 * e] : ei[E + e];
            bool ok = (unsigned)dd < (unsigned)N;
            int l = ok ? atomicAdd(&deg[dd], 1) : 0;
            tmp[e] = make_int2(ok ? dd : -1, l);
        }
    }
}

// ---- 3-phase parallel exclusive scan of deg -> row_ptr (+ dinv/nself) ----

__global__ __launch_bounds__(256) void k_bsum(const int* __restrict__ deg, int n,
                                              int* __restrict__ bsum) {
    int base = blockIdx.x * 1024;
    int local = 0;
#pragma unroll
    for (int j = 0; j < 4; ++j) {
        int idx = base + threadIdx.x + j * 256;
        if (idx < n) local += deg[idx];
    }
    __shared__ int s[4];
#pragma unroll
    for (int off = 32; off; off >>= 1) local += __shfl_down(local, off, 64);
    if ((threadIdx.x & 63) == 0) s[threadIdx.x >> 6] = local;
    __syncthreads();
    if (threadIdx.x == 0) bsum[blockIdx.x] = s[0] + s[1] + s[2] + s[3];
}

__global__ __launch_bounds__(256) void k_bscan(int* __restrict__ bsum, int nb) {
    __shared__ int s[256];
    int t = threadIdx.x;
    int v = (t < nb) ? bsum[t] : 0;
    s[t] = v;
    __syncthreads();
    for (int off = 1; off < 256; off <<= 1) {
        int u = (t >= off) ? s[t - off] : 0;
        __syncthreads();
        s[t] += u;
        __syncthreads();
    }
    if (t < nb) bsum[t] = s[t] - v;   // exclusive
}

__global__ __launch_bounds__(256) void k_rowptr(const int* __restrict__ deg,
                                                const int* __restrict__ boff, int n,
                                                int* __restrict__ row_ptr,
                                                float* __restrict__ dinv,
                                                float* __restrict__ nself) {
    __shared__ int s[256];
    int t = threadIdx.x;
    int base = blockIdx.x * 1024 + t * 4;
    int v0 = (base + 0 < n) ? deg[base + 0] : 0;
    int v1 = (base + 1 < n) ? deg[base + 1] : 0;
    int v2 = (base + 2 < n) ? deg[base + 2] : 0;
    int v3 = (base + 3 < n) ? deg[base + 3] : 0;
    int tot = v0 + v1 + v2 + v3;
    s[t] = tot;
    __syncthreads();
    for (int off = 1; off < 256; off <<= 1) {
        int u = (t >= off) ? s[t - off] : 0;
        __syncthreads();
        s[t] += u;
        __syncthreads();
    }
    int run = boff[blockIdx.x] + ((t == 0) ? 0 : s[t - 1]);
    int vals[4] = {v0, v1, v2, v3};
#pragma unroll
    for (int j = 0; j < 4; ++j) {
        int idx = base + j;
        if (idx < n) {
            row_ptr[idx] = run;
            run += vals[j];
            float df = (float)vals[j] + 1.0f;
            dinv[idx] = rsqrtf(df);
            nself[idx] = 1.0f / df;
        }
    }
    if (blockIdx.x == gridDim.x - 1 && t == 255) row_ptr[n] = boff[blockIdx.x] + s[255];
}

// ---------------- scatter CSR (NO atomics): pos = row_ptr[d] + rank ----------------
__global__ void k_scatter(const int* __restrict__ ei, int E, int N,
                          const int* __restrict__ flags,
                          const int* __restrict__ row_ptr,
                          const float* __restrict__ dinv,
                          const int2* __restrict__ tmp,
                          uint2* __restrict__ colwgt) {
    int i = blockIdx.x * blockDim.x + threadIdx.x;
    int e0 = i * 4;
    if (e0 >= E) return;
    int is64 = flags[11];
    if (e0 + 3 < E && (E & 3) == 0) {
        int s[4];
        if (is64) {
            int4 sa = *(const int4*)(ei + 2 * e0);
            int4 sb = *(const int4*)(ei + 2 * e0 + 4);
            s[0] = sa.x; s[1] = sa.z; s[2] = sb.x; s[3] = sb.z;
        } else {
            int4 sa = *(const int4*)(ei + e0);
            s[0] = sa.x; s[1] = sa.y; s[2] = sa.z; s[3] = sa.w;
        }
        int4 t01 = *(const int4*)(tmp + e0);
        int4 t23 = *(const int4*)(tmp + e0 + 2);
        int d[4] = {t01.x, t01.z, t23.x, t23.z};
        int l[4] = {t01.y, t01.w, t23.y, t23.w};
        int ss[4]; int pos[4]; float wv[4];
#pragma unroll
        for (int k = 0; k < 4; ++k)
            ss[k] = ((unsigned)s[k] < (unsigned)N) ? s[k] : 0;
#pragma unroll
        for (int k = 0; k < 4; ++k) {
            if (d[k] >= 0) {
                pos[k] = row_ptr[d[k]] + l[k];
                wv[k] = dinv[ss[k]] * dinv[d[k]];
            }
        }
#pragma unroll
        for (int k = 0; k < 4; ++k) {
            if (d[k] >= 0) {
                uint2 pk;
                pk.x = (uint_t)ss[k];
                pk.y = __float_as_uint(wv[k]);
                colwgt[pos[k]] = pk;
            }
        }
    } else {
        for (int e = e0; e < E && e < e0 + 4; ++e) {
            int sv = is64 ? ei[2 * e] : ei[e];
            int2 tv = tmp[e];
            if (tv.x >= 0) {
                int ssv = ((unsigned)sv < (unsigned)N) ? sv : 0;
                uint2 pk;
                pk.x = (uint_t)ssv;
                pk.y = __float_as_uint(dinv[ssv] * dinv[tv.x]);
                colwgt[row_ptr[tv.x] + tv.y] = pk;
            }
        }
    }
}

// ===== LDS-staged GEMM, 64 rows/block =====

template <int NCT>
__device__ __forceinline__ void stage_B(const ushort_t* __restrict__ WT, uint4* lds) {
    int t = threadIdx.x;
#pragma unroll
    for (int i = 0; i < NCT; ++i) {
        int g = i * 256 + t;
        uint4 v = ((const uint4*)WT)[g];
        int col = g >> 4, k8 = g & 15;
        int c = col >> 4, l16c = col & 15;
        int kk = k8 >> 2, q = k8 & 3;
        lds[((kk * NCT + c) << 6) + (q << 4) + l16c] = v;
    }
    __syncthreads();
}

__device__ __forceinline__ void load_A1(const void* __restrict__ A, int a16,
                                        int ar, int quad, bf16x8 af[4]) {
    if (a16) {
        const ushort_t* p = (const ushort_t*)A + (size_t)ar * 128 + quad * 8;
#pragma unroll
        for (int kk = 0; kk < 4; ++kk) af[kk] = *(const bf16x8*)(p + kk * 32);
    } else {
        const float* p = (const float*)A + (size_t)ar * 128 + quad * 8;
#pragma unroll
        for (int kk = 0; kk < 4; ++kk) {
            f32x4 u0 = *(const f32x4*)(p + kk * 32);
            f32x4 u1 = *(const f32x4*)(p + kk * 32 + 4);
#pragma unroll
            for (int j = 0; j < 4; ++j) {
                BFU e;
                e.u = f2bf(u0[j]); af[kk][j] = e.h;
                e.u = f2bf(u1[j]); af[kk][j + 4] = e.h;
            }
        }
    }
}

template <int NCT>
__global__ __launch_bounds__(256, 4) void k_gemm2(const void* __restrict__ A, int aFid, int aFix,
                                                  const ushort_t* __restrict__ WT,
                                                  const void* __restrict__ bias, int bFid,
                                                  void* __restrict__ C, int cFix,
                                                  int M, const int* __restrict__ flags) {
    __shared__ uint4 lds[NCT * 256];
    stage_B<NCT>(WT, lds);

    const int F = NCT * 16;
    int t = threadIdx.x;
    int wave = t >> 6, lane = t & 63;
    int quad = lane >> 4, l16 = lane & 15;
    int row0 = blockIdx.x * 64 + wave * 16;

    int a16 = (aFid >= 0) ? flags[aFid] : aFix;
    int ar = row0 + l16; if (ar >= M) ar = M - 1;

    bf16x8 af[4];
    load_A1(A, a16, ar, quad, af);

    f32x4 acc[NCT];
#pragma unroll
    for (int c = 0; c < NCT; ++c) acc[c] = (f32x4){0.f, 0.f, 0.f, 0.f};

#pragma unroll
    for (int kk = 0; kk < 4; ++kk) {
#pragma unroll
        for (int c = 0; c < NCT; ++c) {
            bf16x8 b = *(const bf16x8*)&lds[((kk * NCT + c) << 6) + lane];
            acc[c] = __builtin_amdgcn_mfma_f32_16x16x32_bf16(af[kk], b, acc[c], 0, 0, 0);
        }
    }

    int bf = (bias && bFid >= 0) ? flags[bFid] : 1;
#pragma unroll
    for (int c = 0; c < NCT; ++c) {
        int colg = c * 16 + l16;
        float bv = bias ? loadF(bias, colg, bf) : 0.0f;
#pragma unroll
        for (int q = 0; q < 4; ++q) {
            int row = row0 + quad * 4 + q;
            if (row < M) {
                float v = acc[c][q] + bv;
                if (cFix) ((ushort_t*)C)[(size_t)row * F + colg] = f2bf(v);
                else      ((float*)C)[(size_t)row * F + colg] = v;
            }
        }
    }
}

// layer-1 dual output, two-phase staging (32 KB LDS)
__global__ __launch_bounds__(256, 4) void k_gemm_l1(const void* __restrict__ A,
                                                    const ushort_t* __restrict__ Tcat,
                                                    const void* __restrict__ bres,
                                                    ushort_t* __restrict__ Hout,
                                                    ushort_t* __restrict__ Xres,
                                                    int M, const int* __restrict__ flags) {
    __shared__ uint4 lds[8 * 256];
    int t = threadIdx.x;
    int wave = t >> 6, lane = t & 63;
    int quad = lane >> 4, l16 = lane & 15;
    int row0 = blockIdx.x * 64 + wave * 16;

    int a16 = flags[0];
    int ar = row0 + l16; if (ar >= M) ar = M - 1;

    bf16x8 af[4];
    load_A1(A, a16, ar, quad, af);

    stage_B<8>(Tcat, lds);
    {
        f32x4 acc[8];
#pragma unroll
        for (int c = 0; c < 8; ++c) acc[c] = (f32x4){0.f, 0.f, 0.f, 0.f};
#pragma unroll
        for (int kk = 0; kk < 4; ++kk) {
#pragma unroll
            for (int c = 0; c < 8; ++c) {
                bf16x8 b = *(const bf16x8*)&lds[((kk * 8 + c) << 6) + lane];
                acc[c] = __builtin_amdgcn_mfma_f32_16x16x32_bf16(af[kk], b, acc[c], 0, 0, 0);
            }
        }
#pragma unroll
        for (int c = 0; c < 8; ++c) {
            int colg = c * 16 + l16;
#pragma unroll
            for (int q = 0; q < 4; ++q) {
                int row = row0 + quad * 4 + q;
                if (row < M) Hout[(size_t)row * 128 + colg] = f2bf(acc[c][q]);
            }
        }
    }
    __syncthreads();

    stage_B<8>(Tcat + 128 * 128, lds);
    {
        int bf = flags[8];
        f32x4 acc[8];
#pragma unroll
        for (int c = 0; c < 8; ++c) acc[c] = (f32x4){0.f, 0.f, 0.f, 0.f};
#pragma unroll
        for (int kk = 0; kk < 4; ++kk) {
#pragma unroll
            for (int c = 0; c < 8; ++c) {
                bf16x8 b = *(const bf16x8*)&lds[((kk * 8 + c) << 6) + lane];
                acc[c] = __builtin_amdgcn_mfma_f32_16x16x32_bf16(af[kk], b, acc[c], 0, 0, 0);
            }
        }
#pragma unroll
        for (int c = 0; c < 8; ++c) {
            int colg = c * 16 + l16;
            float bv = loadF(bres, colg, bf);
#pragma unroll
            for (int q = 0; q < 4; ++q) {
                int row = row0 + quad * 4 + q;
                if (row < M) Xres[(size_t)row * 128 + colg] = f2bf(acc[c][q] + bv);
            }
        }
    }
}

// ---------------- aggregation v3: quad-gather, 4 edges per load instruction ----------------
// One wave per node. Quad q handles edges base+4k+q; lane loads uint4 (8 feats, 16B);
// 16 lanes x 16B = one 256B row per quad -> 4 rows per instruction. Metadata read
// directly per-lane (same addr within quad -> HW broadcast). NO shfl in the loop.
// Per-quad partials reduced via shfl_xor(16,32) once at node end.
__global__ __launch_bounds__(256) void k_agg(const ushort_t* __restrict__ H,
                                             const int* __restrict__ row_ptr,
                                             const uint2* __restrict__ colwgt,
                                             const float* __restrict__ nself,
                                             const void* __restrict__ bias, int bFid,
                                             const ushort_t* __restrict__ other,
                                             ushort_t* __restrict__ Out,
                                             int n, const int* __restrict__ flags) {
    int node = (blockIdx.x * blockDim.x + threadIdx.x) >> 6;
    if (node >= n) return;
    int lane = threadIdx.x & 63;
    int quad = lane >> 4;
    int l16 = lane & 15;

    float acc[8];
#pragma unroll
    for (int i = 0; i < 8; ++i) acc[i] = 0.0f;

    int beg = row_ptr[node], end = row_ptr[node + 1];
    for (int base = beg; base < end; base += 16) {
        int e[4]; uint2 m[4];
#pragma unroll
        for (int k = 0; k < 4; ++k) {
            int ee = base + k * 4 + quad;
            e[k] = (ee < end) ? ee : (end - 1);
        }
#pragma unroll
        for (int k = 0; k < 4; ++k) m[k] = colwgt[e[k]];
        int s[4]; float w[4];
#pragma unroll
        for (int k = 0; k < 4; ++k) {
            int ee = base + k * 4 + quad;
            s[k] = (int)m[k].x;
            w[k] = (ee < end) ? __uint_as_float(m[k].y) : 0.0f;
        }
        uint4 v[4];
#pragma unroll
        for (int k = 0; k < 4; ++k)
            v[k] = *(const uint4*)(H + (size_t)s[k] * 128 + l16 * 8);
#pragma unroll
        for (int k = 0; k < 4; ++k) {
            acc[0] = fmaf(bf2f(v[k].x & 0xffffu), w[k], acc[0]);
            acc[1] = fmaf(bf2f(v[k].x >> 16),     w[k], acc[1]);
            acc[2] = fmaf(bf2f(v[k].y & 0xffffu), w[k], acc[2]);
            acc[3] = fmaf(bf2f(v[k].y >> 16),     w[k], acc[3]);
            acc[4] = fmaf(bf2f(v[k].z & 0xffffu), w[k], acc[4]);
            acc[5] = fmaf(bf2f(v[k].z >> 16),     w[k], acc[5]);
            acc[6] = fmaf(bf2f(v[k].w & 0xffffu), w[k], acc[6]);
            acc[7] = fmaf(bf2f(v[k].w >> 16),     w[k], acc[7]);
        }
    }

    // reduce quad partials (lanes l16, +16, +32, +48)
#pragma unroll
    for (int i = 0; i < 8; ++i) {
        acc[i] += __shfl_xor(acc[i], 16, 64);
        acc[i] += __shfl_xor(acc[i], 32, 64);
    }

    if (quad == 0) {
        size_t nidx = (size_t)node * 128 + l16 * 8;
        float ns = nself[node];
        uint4 hv = *(const uint4*)(H + nidx);
        acc[0] += bf2f(hv.x & 0xffffu) * ns;
        acc[1] += bf2f(hv.x >> 16)     * ns;
        acc[2] += bf2f(hv.y & 0xffffu) * ns;
        acc[3] += bf2f(hv.y >> 16)     * ns;
        acc[4] += bf2f(hv.z & 0xffffu) * ns;
        acc[5] += bf2f(hv.z >> 16)     * ns;
        acc[6] += bf2f(hv.w & 0xffffu) * ns;
        acc[7] += bf2f(hv.w >> 16)     * ns;

        int bfm = flags[bFid];
#pragma unroll
        for (int i = 0; i < 8; ++i) acc[i] += loadF(bias, l16 * 8 + i, bfm);
        if (other) {
            uint4 ov = *(const uint4*)(other + nidx);
            acc[0] += bf2f(ov.x & 0xffffu);
            acc[1] += bf2f(ov.x >> 16);
            acc[2] += bf2f(ov.y & 0xffffu);
            acc[3] += bf2f(ov.y >> 16);
            acc[4] += bf2f(ov.z & 0xffffu);
            acc[5] += bf2f(ov.z >> 16);
            acc[6] += bf2f(ov.w & 0xffffu);
            acc[7] += bf2f(ov.w >> 16);
        }
#pragma unroll
        for (int i = 0; i < 8; ++i) acc[i] = fmaxf(acc[i], 0.0f);

        uint4 o;
        o.x = (uint_t)f2bf(acc[0]) | ((uint_t)f2bf(acc[1]) << 16);
        o.y = (uint_t)f2bf(acc[2]) | ((uint_t)f2bf(acc[3]) << 16);
        o.z = (uint_t)f2bf(acc[4]) | ((uint_t)f2bf(acc[5]) << 16);
        o.w = (uint_t)f2bf(acc[6]) | ((uint_t)f2bf(acc[7]) << 16);
        *(uint4*)(Out + nidx) = o;
    }
}

// ---------------- launch ----------------

extern "C" void kernel_launch(void* const* d_in, const int* in_sizes, int n_in,
                              void* d_out, int out_size, void* d_ws, size_t ws_size,
                              hipStream_t stream) {
    const int N = in_sizes[0] / 128;
    const int E = in_sizes[1] / 2;

    const void* x  = d_in[0];
    const int*  ei = (const int*)d_in[1];

    char* ws = (char*)d_ws;
    size_t used = 0;
    auto alloc = [&](size_t bytes) {
        char* p = ws + used;
        used += (bytes + 255) & ~(size_t)255;
        return p;
    };

    int*   flags   = (int*)alloc(64 * 4);
    int*   deg     = (int*)alloc((size_t)N * 4);
    int*   row_ptr = (int*)alloc((size_t)(N + 1) * 4);
    float* dinv    = (float*)alloc((size_t)N * 4);
    float* nself   = (float*)alloc((size_t)N * 4);
    int2*  tmp     = (int2*)alloc((size_t)E * 8);
    uint2* colwgt  = (uint2*)alloc((size_t)E * 8);
    int*   bsum    = (int*)alloc(256 * 4);
    ushort_t* Tcat = (ushort_t*)alloc(256 * 128 * 2);
    ushort_t* T2   = (ushort_t*)alloc(128 * 128 * 2);
    ushort_t* T3   = (ushort_t*)alloc(128 * 128 * 2);
    ushort_t* Tlin = (ushort_t*)alloc(128 * 64 * 2);

    ushort_t* Hbuf = (ushort_t*)alloc((size_t)N * 128 * 2);
    ushort_t* Act1 = (ushort_t*)alloc((size_t)N * 128 * 2);
    ushort_t* Act2 = (ushort_t*)alloc((size_t)N * 128 * 2);
    ushort_t* Xres = (ushort_t*)alloc((size_t)N * 128 * 2);

    if (used > ws_size) return;

    DetectArgs da;
    for (int i = 0; i < 11; ++i) { da.t[i] = d_in[i == 0 ? 0 : i + 1]; da.elems[i] = in_sizes[i == 0 ? 0 : i + 1]; }
    da.ei = ei;
    da.flags = flags;

    const int B = 256;
    int gE4   = ((E + 3) / 4 + B - 1) / B;
    int gPack = (4 * 128 * 128 + 128 * 64) / B;
    int gGemm = (N + 63) / 64;
    int gAgg  = (N + 3) / 4;
    int nb    = (N + 1023) / 1024;

    hipMemsetAsync(deg, 0, (size_t)N * 4, stream);
    k_pack<<<gPack, B, 0, stream>>>(da, Tcat, T2, T3, Tlin);
    k_deg<<<gE4, B, 0, stream>>>(ei, E, N, flags, deg, tmp);
    k_bsum<<<nb, B, 0, stream>>>(deg, N, bsum);
    k_bscan<<<1, B, 0, stream>>>(bsum, nb);
    k_rowptr<<<nb, B, 0, stream>>>(deg, bsum, N, row_ptr, dinv, nself);
    k_scatter<<<gE4, B, 0, stream>>>(ei, E, N, flags, row_ptr, dinv, tmp, colwgt);

    // layer 1 (two-phase dual GEMM): H = x@W1 (bf16), Xres = x@Wres + bres (bf16)
    k_gemm_l1<<<gGemm, B, 0, stream>>>(x, Tcat, d_in[9], Hbuf, Xres, N, flags);
    k_agg<<<gAgg, B, 0, stream>>>(Hbuf, row_ptr, colwgt, nself, d_in[3], 2,
                                  Xres, Act1, N, flags);

    // layer 2
    k_gemm2<8><<<gGemm, B, 0, stream>>>(Act1, -1, 1, T2, nullptr, -1, Hbuf, 1, N, flags);
    k_agg<<<gAgg, B, 0, stream>>>(Hbuf, row_ptr, colwgt, nself, d_in[5], 4,
                                  nullptr, Act2, N, flags);

    // layer 3
    k_gemm2<8><<<gGemm, B, 0, stream>>>(Act2, -1, 1, T3, nullptr, -1, Hbuf, 1, N, flags);
    k_agg<<<gAgg, B, 0, stream>>>(Hbuf, row_ptr, colwgt, nself, d_in[7], 6,
                                  nullptr, Act1, N, flags);

    // final: out = Act1@Wlin + blin (fp32 out)
    k_gemm2<4><<<gGemm, B, 0, stream>>>(Act1, -1, 1, Tlin, d_in[11], 10,
                                        d_out, 0, N, flags);
}

// Round 14
// 300.389 us; speedup vs baseline: 1.0508x; 1.0508x over previous
//
#include <hip/hip_runtime.h>

typedef unsigned short ushort_t;
typedef unsigned int uint_t;

typedef __bf16 bf16x8 __attribute__((ext_vector_type(8)));
typedef float f32x4 __attribute__((ext_vector_type(4)));

union BFU { ushort_t u; __bf16 h; };

__device__ __forceinline__ float bf2f(uint_t u) {
    union { uint_t i; float f; } v; v.i = u << 16; return v.f;
}
__device__ __forceinline__ ushort_t f2bf(float f) {
    union { float f; uint_t i; } v; v.f = f;
    uint_t r = v.i + 0x7fffu + ((v.i >> 16) & 1u);
    return (ushort_t)(r >> 16);
}
// mode: 1 = bf16 storage, 0 = fp32 storage
__device__ __forceinline__ float loadF(const void* p, size_t i, int isBf16) {
    return isBf16 ? bf2f((uint_t)((const ushort_t*)p)[i]) : ((const float*)p)[i];
}

// flags[0..10]: x,W1,b1,W2,b2,W3,b3,Wres,bres,Wlin,blin  (1=bf16, 0=fp32)
// flags[11]: edge_index is int64 (1) or int32 (0)
struct DetectArgs {
    const void* t[11];
    int elems[11];
    const int* ei;
    int* flags;
};

__device__ __forceinline__ int detect_one(const void* p, int elems) {
    const uint_t* w = (const uint_t*)p;
    int n = elems / 2; if (n > 64) n = 64;
    int cnt = 0;
    for (int k = 0; k < n; ++k) {
        uint_t f = (w[k] >> 7) & 0xFFu;
        cnt += (f >= 100u && f <= 135u);
    }
    return (cnt * 10 >= n * 6) ? 1 : 0;
}

// ---------------- weight pack + dtype detection + deg zeroing ----------------
__global__ void k_pack(DetectArgs a,
                       ushort_t* __restrict__ Tcat, ushort_t* __restrict__ T2,
                       ushort_t* __restrict__ T3, ushort_t* __restrict__ Tl,
                       int* __restrict__ deg, int N) {
    __shared__ int lflag;
    int i = blockIdx.x * blockDim.x + threadIdx.x;
    if (i < N) deg[i] = 0;                         // fused memset
    const int SQ = 128 * 128;
    int m = (i < 4 * SQ) ? (i / SQ) : 4;           // uniform per block (SQ%256==0)
    int fid = (m == 0) ? 1 : (m == 1) ? 3 : (m == 2) ? 5 : (m == 3) ? 7 : 9;
    const void* W = a.t[fid];

    if (threadIdx.x == 0) lflag = detect_one(W, a.elems[fid]);
    if (blockIdx.x == 0 && threadIdx.x >= 64 && threadIdx.x < 75) {
        int t = threadIdx.x - 64;
        a.flags[t] = detect_one(a.t[t], a.elems[t]);
    }
    if (blockIdx.x == 0 && threadIdx.x == 75) {
        int nz = 0;
        for (int k = 0; k < 64; ++k) nz += (a.ei[2 * k + 1] != 0);
        a.flags[11] = (nz == 0) ? 1 : 0;
    }
    __syncthreads();
    int isb = lflag;

    if (i < 4 * SQ) {
        int r = i % SQ;
        int k = r / 128, f = r % 128;
        ushort_t* T = (m == 0) ? Tcat : (m == 1) ? T2 : (m == 2) ? T3 : (Tcat + SQ);
        T[f * 128 + k] = f2bf(loadF(W, (size_t)k * 128 + f, isb));
    } else if (i < 4 * SQ + 128 * 64) {
        int r = i - 4 * SQ;
        int k = r / 64, f = r % 64;
        Tl[f * 128 + k] = f2bf(loadF(W, (size_t)k * 64 + f, isb));
    }
}

// ---------------- degree + rank: the ONLY atomic pass ----------------
__global__ void k_deg(const int* __restrict__ ei, int E, int N,
                      const int* __restrict__ flags, int* __restrict__ deg,
                      int2* __restrict__ tmp) {
    int i = blockIdx.x * blockDim.x + threadIdx.x;
    int e0 = i * 4;
    if (e0 >= E) return;
    int is64 = flags[11];
    if (e0 + 3 < E && (E & 3) == 0) {
        int d[4];
        if (is64) {
            int4 va = *(const int4*)(ei + 2 * E + 2 * e0);
            int4 vb = *(const int4*)(ei + 2 * E + 2 * e0 + 4);
            d[0] = va.x; d[1] = va.z; d[2] = vb.x; d[3] = vb.z;
        } else {
            int4 va = *(const int4*)(ei + E + e0);
            d[0] = va.x; d[1] = va.y; d[2] = va.z; d[3] = va.w;
        }
        int l[4]; bool ok[4];
#pragma unroll
        for (int k = 0; k < 4; ++k) ok[k] = (unsigned)d[k] < (unsigned)N;
#pragma unroll
        for (int k = 0; k < 4; ++k)
            l[k] = ok[k] ? atomicAdd(&deg[d[k]], 1) : 0;
        int4 t01, t23;
        t01.x = ok[0] ? d[0] : -1; t01.y = l[0];
        t01.z = ok[1] ? d[1] : -1; t01.w = l[1];
        t23.x = ok[2] ? d[2] : -1; t23.y = l[2];
        t23.z = ok[3] ? d[3] : -1; t23.w = l[3];
        *(int4*)(tmp + e0) = t01;
        *(int4*)(tmp + e0 + 2) = t23;
    } else {
        for (int e = e0; e < E && e < e0 + 4; ++e) {
            int dd = is64 ? ei[2 * E + 2 * e] : ei[E + e];
            bool ok = (unsigned)dd < (unsigned)N;
            int l = ok ? atomicAdd(&deg[dd], 1) : 0;
            tmp[e] = make_int2(ok ? dd : -1, l);
        }
    }
}

// ---- scan: k_bsum (per-1024-chunk sums) + k_rowptr (self-computed offset) ----

__global__ __launch_bounds__(256) void k_bsum(const int* __restrict__ deg, int n,
                                              int* __restrict__ bsum) {
    int base = blockIdx.x * 1024;
    int local = 0;
#pragma unroll
    for (int j = 0; j < 4; ++j) {
        int idx = base + threadIdx.x + j * 256;
        if (idx < n) local += deg[idx];
    }
    __shared__ int s[4];
#pragma unroll
    for (int off = 32; off; off >>= 1) local += __shfl_down(local, off, 64);
    if ((threadIdx.x & 63) == 0) s[threadIdx.x >> 6] = local;
    __syncthreads();
    if (threadIdx.x == 0) bsum[blockIdx.x] = s[0] + s[1] + s[2] + s[3];
}

// computes own block offset by reducing bsum[0..b-1] (nb <= 64, single wave)
__global__ __launch_bounds__(256) void k_rowptr(const int* __restrict__ deg,
                                                const int* __restrict__ bsum, int n,
                                                int* __restrict__ row_ptr,
                                                float* __restrict__ dinv,
                                                float* __restrict__ nself) {
    __shared__ int s[256];
    __shared__ int sboff;
    int t = threadIdx.x;

    if (t < 64) {
        int v = (t < blockIdx.x) ? bsum[t] : 0;   // exclusive: blocks before me
#pragma unroll
        for (int off = 32; off; off >>= 1) v += __shfl_down(v, off, 64);
        if (t == 0) sboff = v;
    }

    int base = blockIdx.x * 1024 + t * 4;
    int v0 = (base + 0 < n) ? deg[base + 0] : 0;
    int v1 = (base + 1 < n) ? deg[base + 1] : 0;
    int v2 = (base + 2 < n) ? deg[base + 2] : 0;
    int v3 = (base + 3 < n) ? deg[base + 3] : 0;
    int tot = v0 + v1 + v2 + v3;
    s[t] = tot;
    __syncthreads();
    for (int off = 1; off < 256; off <<= 1) {
        int u = (t >= off) ? s[t - off] : 0;
        __syncthreads();
        s[t] += u;
        __syncthreads();
    }
    int run = sboff + ((t == 0) ? 0 : s[t - 1]);
    int vals[4] = {v0, v1, v2, v3};
#pragma unroll
    for (int j = 0; j < 4; ++j) {
        int idx = base + j;
        if (idx < n) {
            row_ptr[idx] = run;
            run += vals[j];
            float df = (float)vals[j] + 1.0f;
            dinv[idx] = rsqrtf(df);
            nself[idx] = 1.0f / df;
        }
    }
    if (blockIdx.x == gridDim.x - 1 && t == 255) row_ptr[n] = sboff + s[255];
}

// ---------------- scatter CSR (NO atomics): pos = row_ptr[d] + rank ----------------
__global__ void k_scatter(const int* __restrict__ ei, int E, int N,
                          const int* __restrict__ flags,
                          const int* __restrict__ row_ptr,
                          const float* __restrict__ dinv,
                          const int2* __restrict__ tmp,
                          uint2* __restrict__ colwgt) {
    int i = blockIdx.x * blockDim.x + threadIdx.x;
    int e0 = i * 4;
    if (e0 >= E) return;
    int is64 = flags[11];
    if (e0 + 3 < E && (E & 3) == 0) {
        int s[4];
        if (is64) {
            int4 sa = *(const int4*)(ei + 2 * e0);
            int4 sb = *(const int4*)(ei + 2 * e0 + 4);
            s[0] = sa.x; s[1] = sa.z; s[2] = sb.x; s[3] = sb.z;
        } else {
            int4 sa = *(const int4*)(ei + e0);
            s[0] = sa.x; s[1] = sa.y; s[2] = sa.z; s[3] = sa.w;
        }
        int4 t01 = *(const int4*)(tmp + e0);
        int4 t23 = *(const int4*)(tmp + e0 + 2);
        int d[4] = {t01.x, t01.z, t23.x, t23.z};
        int l[4] = {t01.y, t01.w, t23.y, t23.w};
        int ss[4]; int pos[4]; float wv[4];
#pragma unroll
        for (int k = 0; k < 4; ++k)
            ss[k] = ((unsigned)s[k] < (unsigned)N) ? s[k] : 0;
#pragma unroll
        for (int k = 0; k < 4; ++k) {
            if (d[k] >= 0) {
                pos[k] = row_ptr[d[k]] + l[k];
                wv[k] = dinv[ss[k]] * dinv[d[k]];
            }
        }
#pragma unroll
        for (int k = 0; k < 4; ++k) {
            if (d[k] >= 0) {
                uint2 pk;
                pk.x = (uint_t)ss[k];
                pk.y = __float_as_uint(wv[k]);
                colwgt[pos[k]] = pk;
            }
        }
    } else {
        for (int e = e0; e < E && e < e0 + 4; ++e) {
            int sv = is64 ? ei[2 * e] : ei[e];
            int2 tv = tmp[e];
            if (tv.x >= 0) {
                int ssv = ((unsigned)sv < (unsigned)N) ? sv : 0;
                uint2 pk;
                pk.x = (uint_t)ssv;
                pk.y = __float_as_uint(dinv[ssv] * dinv[tv.x]);
                colwgt[row_ptr[tv.x] + tv.y] = pk;
            }
        }
    }
}

// ===== LDS-staged GEMM, 64 rows/block =====

template <int NCT>
__device__ __forceinline__ void stage_B(const ushort_t* __restrict__ WT, uint4* lds) {
    int t = threadIdx.x;
#pragma unroll
    for (int i = 0; i < NCT; ++i) {
        int g = i * 256 + t;
        uint4 v = ((const uint4*)WT)[g];
        int col = g >> 4, k8 = g & 15;
        int c = col >> 4, l16c = col & 15;
        int kk = k8 >> 2, q = k8 & 3;
        lds[((kk * NCT + c) << 6) + (q << 4) + l16c] = v;
    }
    __syncthreads();
}

__device__ __forceinline__ void load_A1(const void* __restrict__ A, int a16,
                                        int ar, int quad, bf16x8 af[4]) {
    if (a16) {
        const ushort_t* p = (const ushort_t*)A + (size_t)ar * 128 + quad * 8;
#pragma unroll
        for (int kk = 0; kk < 4; ++kk) af[kk] = *(const bf16x8*)(p + kk * 32);
    } else {
        const float* p = (const float*)A + (size_t)ar * 128 + quad * 8;
#pragma unroll
        for (int kk = 0; kk < 4; ++kk) {
            f32x4 u0 = *(const f32x4*)(p + kk * 32);
            f32x4 u1 = *(const f32x4*)(p + kk * 32 + 4);
#pragma unroll
            for (int j = 0; j < 4; ++j) {
                BFU e;
                e.u = f2bf(u0[j]); af[kk][j] = e.h;
                e.u = f2bf(u1[j]); af[kk][j + 4] = e.h;
            }
        }
    }
}

template <int NCT>
__global__ __launch_bounds__(256, 4) void k_gemm2(const void* __restrict__ A, int aFid, int aFix,
                                                  const ushort_t* __restrict__ WT,
                                                  const void* __restrict__ bias, int bFid,
                                                  void* __restrict__ C, int cFix,
                                                  int M, const int* __restrict__ flags) {
    __shared__ uint4 lds[NCT * 256];
    stage_B<NCT>(WT, lds);

    const int F = NCT * 16;
    int t = threadIdx.x;
    int wave = t >> 6, lane = t & 63;
    int quad = lane >> 4, l16 = lane & 15;
    int row0 = blockIdx.x * 64 + wave * 16;

    int a16 = (aFid >= 0) ? flags[aFid] : aFix;
    int ar = row0 + l16; if (ar >= M) ar = M - 1;

    bf16x8 af[4];
    load_A1(A, a16, ar, quad, af);

    f32x4 acc[NCT];
#pragma unroll
    for (int c = 0; c < NCT; ++c) acc[c] = (f32x4){0.f, 0.f, 0.f, 0.f};

#pragma unroll
    for (int kk = 0; kk < 4; ++kk) {
#pragma unroll
        for (int c = 0; c < NCT; ++c) {
            bf16x8 b = *(const bf16x8*)&lds[((kk * NCT + c) << 6) + lane];
            acc[c] = __builtin_amdgcn_mfma_f32_16x16x32_bf16(af[kk], b, acc[c], 0, 0, 0);
        }
    }

    int bf = (bias && bFid >= 0) ? flags[bFid] : 1;
#pragma unroll
    for (int c = 0; c < NCT; ++c) {
        int colg = c * 16 + l16;
        float bv = bias ? loadF(bias, colg, bf) : 0.0f;
#pragma unroll
        for (int q = 0; q < 4; ++q) {
            int row = row0 + quad * 4 + q;
            if (row < M) {
                float v = acc[c][q] + bv;
                if (cFix) ((ushort_t*)C)[(size_t)row * F + colg] = f2bf(v);
                else      ((float*)C)[(size_t)row * F + colg] = v;
            }
        }
    }
}

// layer-1 dual output, two-phase staging (32 KB LDS)
__global__ __launch_bounds__(256, 4) void k_gemm_l1(const void* __restrict__ A,
                                                    const ushort_t* __restrict__ Tcat,
                                                    const void* __restrict__ bres,
                                                    ushort_t* __restrict__ Hout,
                                                    ushort_t* __restrict__ Xres,
                                                    int M, const int* __restrict__ flags) {
    __shared__ uint4 lds[8 * 256];
    int t = threadIdx.x;
    int wave = t >> 6, lane = t & 63;
    int quad = lane >> 4, l16 = lane & 15;
    int row0 = blockIdx.x * 64 + wave * 16;

    int a16 = flags[0];
    int ar = row0 + l16; if (ar >= M) ar = M - 1;

    bf16x8 af[4];
    load_A1(A, a16, ar, quad, af);

    stage_B<8>(Tcat, lds);
    {
        f32x4 acc[8];
#pragma unroll
        for (int c = 0; c < 8; ++c) acc[c] = (f32x4){0.f, 0.f, 0.f, 0.f};
#pragma unroll
        for (int kk = 0; kk < 4; ++kk) {
#pragma unroll
            for (int c = 0; c < 8; ++c) {
                bf16x8 b = *(const bf16x8*)&lds[((kk * 8 + c) << 6) + lane];
                acc[c] = __builtin_amdgcn_mfma_f32_16x16x32_bf16(af[kk], b, acc[c], 0, 0, 0);
            }
        }
#pragma unroll
        for (int c = 0; c < 8; ++c) {
            int colg = c * 16 + l16;
#pragma unroll
            for (int q = 0; q < 4; ++q) {
                int row = row0 + quad * 4 + q;
                if (row < M) Hout[(size_t)row * 128 + colg] = f2bf(acc[c][q]);
            }
        }
    }
    __syncthreads();

    stage_B<8>(Tcat + 128 * 128, lds);
    {
        int bf = flags[8];
        f32x4 acc[8];
#pragma unroll
        for (int c = 0; c < 8; ++c) acc[c] = (f32x4){0.f, 0.f, 0.f, 0.f};
#pragma unroll
        for (int kk = 0; kk < 4; ++kk) {
#pragma unroll
            for (int c = 0; c < 8; ++c) {
                bf16x8 b = *(const bf16x8*)&lds[((kk * 8 + c) << 6) + lane];
                acc[c] = __builtin_amdgcn_mfma_f32_16x16x32_bf16(af[kk], b, acc[c], 0, 0, 0);
            }
        }
#pragma unroll
        for (int c = 0; c < 8; ++c) {
            int colg = c * 16 + l16;
            float bv = loadF(bres, colg, bf);
#pragma unroll
            for (int q = 0; q < 4; ++q) {
                int row = row0 + quad * 4 + q;
                if (row < M) Xres[(size_t)row * 128 + colg] = f2bf(acc[c][q] + bv);
            }
        }
    }
}

// ---------------- aggregation (R12 winner): one wave/node, 16-deep shfl burst ----------------
__global__ __launch_bounds__(256) void k_agg(const ushort_t* __restrict__ H,
                                             const int* __restrict__ row_ptr,
                                             const uint2* __restrict__ colwgt,
                                             const float* __restrict__ nself,
                                             const void* __restrict__ bias, int bFid,
                                             const ushort_t* __restrict__ other,
                                             ushort_t* __restrict__ Out,
                                             int n, const int* __restrict__ flags) {
    int node = (blockIdx.x * blockDim.x + threadIdx.x) >> 6;
    if (node >= n) return;
    int lane = threadIdx.x & 63;
    int f = lane * 2;

    float ns = nself[node];
    size_t nidx = (size_t)node * 128 + f;

    uint_t hv = *(const uint_t*)(H + nidx);
    float a0 = bf2f(hv & 0xffffu) * ns;
    float a1 = bf2f(hv >> 16) * ns;

    int beg = row_ptr[node], end = row_ptr[node + 1];
    for (int bs = beg; bs < end; bs += 64) {
        int rem = end - bs;
        int nb = (rem < 64) ? rem : 64;
        uint2 m = (lane < nb) ? colwgt[bs + lane] : (uint2){0u, 0u};
        int c = (int)m.x;
        float w = __uint_as_float(m.y);

        for (int j = 0; j < nb; j += 16) {
            int si[16]; float wi[16]; uint_t vi[16];
#pragma unroll
            for (int q = 0; q < 16; ++q) {
                si[q] = __shfl(c, j + q, 64);
                wi[q] = __shfl(w, j + q, 64);
            }
#pragma unroll
            for (int q = 0; q < 16; ++q)
                vi[q] = *(const uint_t*)(H + (size_t)si[q] * 128 + f);
#pragma unroll
            for (int q = 0; q < 16; ++q) {
                a0 = fmaf(bf2f(vi[q] & 0xffffu), wi[q], a0);
                a1 = fmaf(bf2f(vi[q] >> 16), wi[q], a1);
            }
        }
    }

    int bfm = flags[bFid];
    a0 += loadF(bias, f, bfm);
    a1 += loadF(bias, f + 1, bfm);
    if (other) {
        uint_t ov = *(const uint_t*)(other + nidx);
        a0 += bf2f(ov & 0xffffu);
        a1 += bf2f(ov >> 16);
    }
    a0 = fmaxf(a0, 0.0f);
    a1 = fmaxf(a1, 0.0f);
    uint_t outv = (uint_t)f2bf(a0) | ((uint_t)f2bf(a1) << 16);
    *(uint_t*)(Out + nidx) = outv;
}

// ---------------- launch ----------------

extern "C" void kernel_launch(void* const* d_in, const int* in_sizes, int n_in,
                              void* d_out, int out_size, void* d_ws, size_t ws_size,
                              hipStream_t stream) {
    const int N = in_sizes[0] / 128;
    const int E = in_sizes[1] / 2;

    const void* x  = d_in[0];
    const int*  ei = (const int*)d_in[1];

    char* ws = (char*)d_ws;
    size_t used = 0;
    auto alloc = [&](size_t bytes) {
        char* p = ws + used;
        used += (bytes + 255) & ~(size_t)255;
        return p;
    };

    int*   flags   = (int*)alloc(64 * 4);
    int*   deg     = (int*)alloc((size_t)N * 4);
    int*   row_ptr = (int*)alloc((size_t)(N + 1) * 4);
    float* dinv    = (float*)alloc((size_t)N * 4);
    float* nself   = (float*)alloc((size_t)N * 4);
    int2*  tmp     = (int2*)alloc((size_t)E * 8);
    uint2* colwgt  = (uint2*)alloc((size_t)E * 8);
    int*   bsum    = (int*)alloc(256 * 4);
    ushort_t* Tcat = (ushort_t*)alloc(256 * 128 * 2);
    ushort_t* T2   = (ushort_t*)alloc(128 * 128 * 2);
    ushort_t* T3   = (ushort_t*)alloc(128 * 128 * 2);
    ushort_t* Tlin = (ushort_t*)alloc(128 * 64 * 2);

    ushort_t* Hbuf = (ushort_t*)alloc((size_t)N * 128 * 2);
    ushort_t* Act1 = (ushort_t*)alloc((size_t)N * 128 * 2);
    ushort_t* Act2 = (ushort_t*)alloc((size_t)N * 128 * 2);
    ushort_t* Xres = (ushort_t*)alloc((size_t)N * 128 * 2);

    if (used > ws_size) return;

    DetectArgs da;
    for (int i = 0; i < 11; ++i) { da.t[i] = d_in[i == 0 ? 0 : i + 1]; da.elems[i] = in_sizes[i == 0 ? 0 : i + 1]; }
    da.ei = ei;
    da.flags = flags;

    const int B = 256;
    int gE4   = ((E + 3) / 4 + B - 1) / B;
    int gPack = (4 * 128 * 128 + 128 * 64) / B;   // 288 blocks = 73728 threads >= N
    int gGemm = (N + 63) / 64;
    int gAgg  = (N + 3) / 4;
    int nb    = (N + 1023) / 1024;                // 49 <= 64 (rowptr self-scan limit)

    k_pack<<<gPack, B, 0, stream>>>(da, Tcat, T2, T3, Tlin, deg, N);
    k_deg<<<gE4, B, 0, stream>>>(ei, E, N, flags, deg, tmp);
    k_bsum<<<nb, B, 0, stream>>>(deg, N, bsum);
    k_rowptr<<<nb, B, 0, stream>>>(deg, bsum, N, row_ptr, dinv, nself);
    k_scatter<<<gE4, B, 0, stream>>>(ei, E, N, flags, row_ptr, dinv, tmp, colwgt);

    // layer 1 (two-phase dual GEMM): H = x@W1 (bf16), Xres = x@Wres + bres (bf16)
    k_gemm_l1<<<gGemm, B, 0, stream>>>(x, Tcat, d_in[9], Hbuf, Xres, N, flags);
    k_agg<<<gAgg, B, 0, stream>>>(Hbuf, row_ptr, colwgt, nself, d_in[3], 2,
                                  Xres, Act1, N, flags);

    // layer 2
    k_gemm2<8><<<gGemm, B, 0, stream>>>(Act1, -1, 1, T2, nullptr, -1, Hbuf, 1, N, flags);
    k_agg<<<gAgg, B, 0, stream>>>(Hbuf, row_ptr, colwgt, nself, d_in[5], 4,
                                  nullptr, Act2, N, flags);

    // layer 3
    k_gemm2<8><<<gGemm, B, 0, stream>>>(Act2, -1, 1, T3, nullptr, -1, Hbuf, 1, N, flags);
    k_agg<<<gAgg, B, 0, stream>>>(Hbuf, row_ptr, colwgt, nself, d_in[7], 6,
                                  nullptr, Act1, N, flags);

    // final: out = Act1@Wlin + blin (fp32 out)
    k_gemm2<4><<<gGemm, B, 0, stream>>>(Act1, -1, 1, Tlin, d_in[11], 10,
                                        d_out, 0, N, flags);
}